// Round 1
// 240.722 us; speedup vs baseline: 1.0016x; 1.0016x over previous
//
#include <hip/hip_runtime.h>
#include <math.h>

#define T_DIM 128
#define H_DIM 16
#define N_DIM 64
#define C_DIM 256
#define S_DIM 129   // 2*64+1
#define LOG_TINY (-87.336544750553109f)
#define NEG_HUGE (-3.0e38f)

__device__ __forceinline__ float logadd_(float a, float b) {
    float m = fmaxf(a, b);
    float d = fminf(a, b) - m;          // <= 0
    return m + __logf(1.0f + __expf(d));
}

// Exact 3-way log-sum-exp. Pass NEG_HUGE for an excluded term:
// __expf(NEG_HUGE - m) underflows to exactly 0 (m >= LOG_TINY always).
__device__ __forceinline__ float lse3_(float a, float b, float c) {
    float m = fmaxf(fmaxf(a, b), c);
    return m + __logf(__expf(a - m) + __expf(b - m) + __expf(c - m));
}

// Kernel 1: for each (t, n): lse[c] = logsumexp_h(classify[t,h,n,c] + mask[t,h,n])
// then compact-gather the only classes the scan needs:
//   Gt[n][t][l] = lse[targets[n][l]]  (l=0..63)   Gb[n][t] = lse[blank=0]
// float4 loads; 134 MB read (HBM floor), 2.1 MB written.  [unchanged — at roofline]
__global__ __launch_bounds__(256) void gc_kernel(
    const float* __restrict__ mask,        // (T,H,N)
    const float* __restrict__ classify,    // (T,H,N,C)
    const int*   __restrict__ targets,     // (N,64)
    float* __restrict__ Gt,                // (N,T,64)
    float* __restrict__ Gb)                // (N,T)
{
    const int t  = blockIdx.x;             // 0..127
    const int ng = blockIdx.y;             // 0..15  (group of 4 n)
    const int nl = threadIdx.x >> 6;       // 0..3
    const int cg = threadIdx.x & 63;       // 0..63
    const int c  = cg * 4;
    const int n  = ng * 4 + nl;

    __shared__ float m_lds[H_DIM][4];      // mask[t,h,n] for the 4 n's
    __shared__ float lse_lds[4][C_DIM];

    if (threadIdx.x < 64) {
        int h  = threadIdx.x >> 2;
        int nn = threadIdx.x & 3;
        m_lds[h][nn] = mask[(t * H_DIM + h) * N_DIM + ng * 4 + nn];
    }
    __syncthreads();

    const float4* base = (const float4*)(classify +
        ((size_t)t * H_DIM * N_DIM + n) * C_DIM + c);
    const size_t hstride = (size_t)N_DIM * C_DIM / 4;   // float4 units

    float4 x[H_DIM];
#pragma unroll
    for (int h = 0; h < H_DIM; ++h) {
        float4 v = base[h * hstride];
        float  m = m_lds[h][nl];
        x[h] = make_float4(v.x + m, v.y + m, v.z + m, v.w + m);
    }
    float4 mx = make_float4(-3.4e38f, -3.4e38f, -3.4e38f, -3.4e38f);
#pragma unroll
    for (int h = 0; h < H_DIM; ++h) {
        mx.x = fmaxf(mx.x, x[h].x); mx.y = fmaxf(mx.y, x[h].y);
        mx.z = fmaxf(mx.z, x[h].z); mx.w = fmaxf(mx.w, x[h].w);
    }
    float4 s = make_float4(0.f, 0.f, 0.f, 0.f);
#pragma unroll
    for (int h = 0; h < H_DIM; ++h) {
        s.x += __expf(x[h].x - mx.x); s.y += __expf(x[h].y - mx.y);
        s.z += __expf(x[h].z - mx.z); s.w += __expf(x[h].w - mx.w);
    }
    lse_lds[nl][c + 0] = mx.x + __logf(s.x);
    lse_lds[nl][c + 1] = mx.y + __logf(s.y);
    lse_lds[nl][c + 2] = mx.z + __logf(s.z);
    lse_lds[nl][c + 3] = mx.w + __logf(s.w);
    __syncthreads();

    // gather phase: thread (nl, l) writes Gt[n][t][l]
    {
        int l  = cg;
        int tv = targets[n * 64 + l];
        Gt[((size_t)n * T_DIM + t) * 64 + l] = lse_lds[nl][tv];
        if (l == 0) Gb[n * T_DIM + t] = lse_lds[nl][0];
    }
}

// Kernel 2: one wave per n. Lane l owns lattice s=2l, 2l+1 (lane 63 also s=128).
// No LDS staging: each step's Gt row is one coalesced 256 B wave-load and Gb a
// uniform scalar load; the 127-step loop is FULLY UNROLLED so the compiler
// hoists loads far ahead of use (addresses are recursion-independent) and the
// HBM/L3 latency hides under the serial LSE chain instead of in front of it.
// Per-step chain shortened via one 3-way LSE (was two sequential 2-way logadds).
__global__ __launch_bounds__(64) void scan_kernel(
    const float* __restrict__ Gt,        // (N,T,64)
    const float* __restrict__ Gb,        // (N,T)
    const int*   __restrict__ targets,   // (N,64)
    const int*   __restrict__ tlen,      // (N,)
    float*       __restrict__ out)       // (N,)
{
    const int n = blockIdx.x;
    const int l = threadIdx.x;           // 0..63

    const float* __restrict__ gtp = Gt + (size_t)n * T_DIM * 64;
    const float* __restrict__ gbp = Gb + (size_t)n * T_DIM;

    int tgt_l = targets[n * 64 + l];
    int tgt_p = __shfl_up(tgt_l, 1, 64);
    unsigned long long D = __ballot(l > 0 && tgt_l != tgt_p);
    // bit l of D: skip flag for odd lattice pos s=2l+1 <=> (tgt[l] != tgt[l-1])
    const int skip1 = (int)((D >> l) & 1ULL) && (l > 0);
    const float pskip = skip1 ? 0.f : NEG_HUGE;   // additive gate: p1 + pskip
                                                   // (NEG_HUGE forces exp->0)

    // v state: s=2l (v0), s=2l+1 (v1), s=128 on lane 63 (v2)
    float v0 = (l == 0) ? 0.f : -1e30f;
    float v1 = (l == 0) ? 0.f : -1e30f;
    float v2 = -1e30f;                   // lane 63 only

    int cc = 2;                          // cc at step i=0

#pragma unroll
    for (int i = 0; i < T_DIM - 1; ++i) {
        if (i >= 1)
            cc += 1 + (int)((i & 1) ? 0ULL : ((D >> (i >> 1)) & 1ULL));

        float gb = gbp[i];                      // uniform -> scalar load
        float gt = gtp[i * 64 + l];             // coalesced 256 B wave load

        float hs0 = fmaxf(v0 + gb, LOG_TINY);
        if (2 * l > cc) hs0 = LOG_TINY;
        float hs1 = fmaxf(v1 + gt, LOG_TINY);
        if (2 * l + 1 > cc) hs1 = LOG_TINY;
        float hs2 = fmaxf(v2 + gb, LOG_TINY);
        if (128 > cc) hs2 = LOG_TINY;           // s=128 (lane 63's value used)

        float p1 = __shfl_up(hs1, 1, 64);       // hs[2l-1]

        // s=2l (even, no skip): v0' = logadd(hs0, hs[2l-1])
        v0 = (l == 0) ? hs0 : logadd_(hs0, p1);
        // s=2l+1: v1' = lse(hs1, hs0 [, hs[2l-1] if skip]) — single 3-way LSE;
        // excluded term is (p1 + NEG_HUGE) -> exp underflows to exactly 0.
        v1 = lse3_(hs1, hs0, fmaxf(p1 + pskip, NEG_HUGE));
        // s=128 (lane 63): v2' = logadd(hs2, hs[127]=own hs1)
        v2 = logadd_(hs2, hs1);
    }

    // res[s] = v[s] + G[T-1, s]
    float gb_f = gbp[T_DIM - 1];
    float gt_f = gtp[(T_DIM - 1) * 64 + l];
    float res0 = v0 + gb_f;              // s = 2l
    float res1 = v1 + gt_f;              // s = 2l+1
    float res2 = v2 + gb_f;              // s = 128 (lane 63)

    int tl = tlen[n];                    // 32..64
    float g1 = (tl == 64) ? __shfl(res2, 63, 64) : __shfl(res0, tl, 64);
    float g2 = __shfl(res1, tl - 1, 64); // s = 2tl-1
    if (l == 0)
        out[n] = -(logadd_(g1, g2) / (float)tl);
}

extern "C" void kernel_launch(void* const* d_in, const int* in_sizes, int n_in,
                              void* d_out, int out_size, void* d_ws, size_t ws_size,
                              hipStream_t stream) {
    const float* mask     = (const float*)d_in[0];   // (T,H,N)
    const float* classify = (const float*)d_in[1];   // (T,H,N,C)
    const int*   targets  = (const int*)d_in[2];     // (N,64)
    // d_in[3] = input_lengths (unused by reference)
    const int*   tlen     = (const int*)d_in[4];     // (N,)
    float*       out      = (float*)d_out;           // (N,)

    float* Gt = (float*)d_ws;                              // 64*128*64*4 = 2 MiB
    float* Gb = (float*)((char*)d_ws + (size_t)N_DIM * T_DIM * 64 * 4); // 32 KiB

    gc_kernel<<<dim3(T_DIM, 16), dim3(256), 0, stream>>>(mask, classify, targets, Gt, Gb);
    scan_kernel<<<dim3(N_DIM), dim3(64), 0, stream>>>(Gt, Gb, targets, tlen, out);
}